// Round 9
// baseline (331.942 us; speedup 1.0000x reference)
//
#include <hip/hip_runtime.h>
#include <hip/hip_bf16.h>
#include <cstdint>

#define B_ 256
#define P_ 196
#define D_ 512
#define A_ 512

#define OUT_CHAT  0
#define OUT_ALPHA (B_*D_)            // 131072
#define OUT_BETA  (B_*D_ + B_*P_)    // 181248

typedef unsigned short ushort_t;
typedef uint32_t u32;
typedef uint64_t u64;
typedef __attribute__((ext_vector_type(8))) __bf16 bf16x8;
typedef __attribute__((ext_vector_type(4))) float f32x4;

__device__ __forceinline__ ushort_t f2bf(float f) {
    union { float f; u32 i; } v; v.f = f;
    u32 r = (v.i + 0x7fffu + ((v.i >> 16) & 1u)) >> 16;
    return (ushort_t)r;
}
__device__ __forceinline__ float bfbits2f(u32 lo16) {
    union { u32 i; float f; } v; v.i = lo16 << 16; return v.f;
}
// HW packed f32->bf16 (v_cvt_pk_bf16_f32 on gfx950)
__device__ __forceinline__ u32 cvt2bf(float x, float y) {
    union { __hip_bfloat162 h; u32 u; } v;
    v.h = __float22bfloat162_rn(make_float2(x, y));
    return v.u;
}
__device__ __forceinline__ float tanh_fast(float x) {
    float e = __expf(2.0f * x);
    return 1.0f - 2.0f / (e + 1.0f);
}
// async 16B global->LDS (global_load_lds_dwordx4); LDS dest is effectively
// wave-uniform base (first lane) + lane*16 — our per-lane lds ptrs match
// that mapping (same idiom as the r0-r2 kernels that passed correctness).
__device__ __forceinline__ void async_load16(const ushort_t* g, ushort_t* l) {
    __builtin_amdgcn_global_load_lds(
        (const __attribute__((address_space(1))) unsigned int*)g,
        (__attribute__((address_space(3))) unsigned int*)l, 16, 0, 0);
}
__device__ __forceinline__ void fma8(float ap, uint4 v, float ac[8]) {
    ac[0] = fmaf(ap, bfbits2f(v.x & 0xffffu), ac[0]);
    ac[1] = fmaf(ap, bfbits2f(v.x >> 16),     ac[1]);
    ac[2] = fmaf(ap, bfbits2f(v.y & 0xffffu), ac[2]);
    ac[3] = fmaf(ap, bfbits2f(v.y >> 16),     ac[3]);
    ac[4] = fmaf(ap, bfbits2f(v.z & 0xffffu), ac[4]);
    ac[5] = fmaf(ap, bfbits2f(v.z >> 16),     ac[5]);
    ac[6] = fmaf(ap, bfbits2f(v.w & 0xffffu), ac[6]);
    ac[7] = fmaf(ap, bfbits2f(v.w >> 16),     ac[7]);
}

// ---- k_prep: [0,12544) Ebf=bf16(E); [12544,12672) dh/st cvt;
//              [12672,13440) transposes WT[a][d]=bf16(W[d][a]) ----
__global__ __launch_bounds__(256) void k_prep(
    const float* __restrict__ E, const float* __restrict__ dh,
    const float* __restrict__ st,
    const float* __restrict__ Wv, const float* __restrict__ Wh,
    const float* __restrict__ Ws,
    ushort_t* __restrict__ Ebf, ushort_t* __restrict__ dhbf,
    ushort_t* __restrict__ stbf,
    ushort_t* __restrict__ WvT, ushort_t* __restrict__ WhT,
    ushort_t* __restrict__ WsT)
{
    __shared__ ushort_t tile[32][33];
    int bx = blockIdx.x;
    if (bx < 12544) {
        size_t i0 = (size_t)bx * 512 + threadIdx.x;
        const float4* src = (const float4*)E;
        u64* dst = (u64*)Ebf;
        float4 v0 = src[i0];
        float4 v1 = src[i0 + 256];
        dst[i0]       = (u64)cvt2bf(v0.x, v0.y) | ((u64)cvt2bf(v0.z, v0.w) << 32);
        dst[i0 + 256] = (u64)cvt2bf(v1.x, v1.y) | ((u64)cvt2bf(v1.z, v1.w) << 32);
    } else if (bx < 12672) {
        int gid = (bx - 12544) * 256 + threadIdx.x;   // 0..32767
        float4 dv = ((const float4*)dh)[gid];
        float4 sv = ((const float4*)st)[gid];
        ((u64*)dhbf)[gid] = (u64)cvt2bf(dv.x, dv.y) | ((u64)cvt2bf(dv.z, dv.w) << 32);
        ((u64*)stbf)[gid] = (u64)cvt2bf(sv.x, sv.y) | ((u64)cvt2bf(sv.z, sv.w) << 32);
    } else {
        int idx = bx - 12672;            // 0..767
        int z   = idx >> 8;              // which matrix
        int rem = idx & 255;
        int tby = rem >> 4, tbx = rem & 15;
        const float* W  = (z == 0) ? Wv  : (z == 1) ? Wh  : Ws;
        ushort_t*    WT = (z == 0) ? WvT : (z == 1) ? WhT : WsT;
        int t = threadIdx.x, r = t >> 5, c = t & 31;
#pragma unroll
        for (int i = 0; i < 4; ++i) {
            int row = r + 8 * i;
            tile[row][c] = f2bf(W[(size_t)(tby * 32 + row) * A_ + tbx * 32 + c]);
        }
        __syncthreads();
#pragma unroll
        for (int i = 0; i < 4; ++i) {
            int row = r + 8 * i;
            WT[(size_t)(tbx * 32 + row) * D_ + tby * 32 + c] = tile[c][row];
        }
    }
}

#define PADK 72   // used by k1 only

// ---- k1_mfma: hidden = dh@Wh+bh (z=0) and s = st@Ws+bs (z=1) ----
__global__ __launch_bounds__(256) void k1_mfma(
    const ushort_t* __restrict__ dhbf, const ushort_t* __restrict__ stbf,
    const ushort_t* __restrict__ WhT,  const ushort_t* __restrict__ WsT,
    const float* __restrict__ bh, const float* __restrict__ bs,
    float* __restrict__ hidden_ws, float* __restrict__ s_ws)
{
    __shared__ ushort_t As[128 * PADK];
    __shared__ ushort_t Bs[128 * PADK];

    int mat = blockIdx.z;
    const ushort_t* Abf = mat ? stbf : dhbf;
    const ushort_t* WT  = mat ? WsT  : WhT;
    const float*    bia = mat ? bs   : bh;
    float*          outp = mat ? s_ws : hidden_ws;

    int tid = threadIdx.x;
    int m0 = blockIdx.y * 128;
    int n0 = blockIdx.x * 128;

    int lane = tid & 63, w = tid >> 6;
    int wm = w & 1, wn = w >> 1;
    int col = lane & 15, q = lane >> 4;

    f32x4 acc[4][4];
#pragma unroll
    for (int tm = 0; tm < 4; ++tm)
#pragma unroll
        for (int tn = 0; tn < 4; ++tn)
            acc[tm][tn] = (f32x4){0.f, 0.f, 0.f, 0.f};

    const ushort_t* arow = As + (wm * 64 + col) * PADK + q * 8;
    const ushort_t* brow = Bs + (wn * 64 + col) * PADK + q * 8;

    int sr = tid >> 3, sc = tid & 7;
    for (int kt = 0; kt < D_ / 64; ++kt) {
#pragma unroll
        for (int i = 0; i < 4; ++i) {
            int row = sr + i * 32;
            *(uint4*)(As + row * PADK + sc * 8) =
                *(const uint4*)(Abf + (size_t)(m0 + row) * D_ + kt * 64 + sc * 8);
            *(uint4*)(Bs + row * PADK + sc * 8) =
                *(const uint4*)(WT + (size_t)(n0 + row) * D_ + kt * 64 + sc * 8);
        }
        __syncthreads();
#pragma unroll
        for (int ks = 0; ks < 2; ++ks) {
            bf16x8 afr[4];
#pragma unroll
            for (int tm = 0; tm < 4; ++tm)
                afr[tm] = *(const bf16x8*)(arow + tm * 16 * PADK + ks * 32);
#pragma unroll
            for (int tn = 0; tn < 4; ++tn) {
                bf16x8 bfr = *(const bf16x8*)(brow + tn * 16 * PADK + ks * 32);
#pragma unroll
                for (int tm = 0; tm < 4; ++tm)
                    acc[tm][tn] = __builtin_amdgcn_mfma_f32_16x16x32_bf16(
                        afr[tm], bfr, acc[tm][tn], 0, 0, 0);
            }
        }
        __syncthreads();
    }

#pragma unroll
    for (int tm = 0; tm < 4; ++tm)
#pragma unroll
        for (int r = 0; r < 4; ++r) {
            int b = m0 + wm * 64 + tm * 16 + q * 4 + r;
#pragma unroll
            for (int tn = 0; tn < 4; ++tn) {
                int n = n0 + wn * 64 + tn * 16 + col;
                outp[(size_t)b * A_ + n] = acc[tm][tn][r] + bia[n];
            }
        }
}

// ---- K2 (traffic-optimal, proven components): BM=64, BN=512 (full N),
// 512 threads (8 waves, 2m x 4n).  r8's traffic win confirmed (FETCH
// 83->36MB) but it spilled (acc=128/thread, WRITE 18MB) and its flat-512
// A layout conflicted (819K).  This version:
//  - acc = 64 f32/thread (r2's spill-free count);
//  - A LDS = r2's EXACT BK=64-chunked layout As[8][64*64], staged with
//    r2's exact global_load_lds map and read with r2's exact swizzled
//    offsets (measured ~0 conflicts in r2/r7) — staged ONCE, 1 barrier;
//  - B read directly from WvT (512KB, L2-resident; per 4-lane group the
//    q*8 offsets make each read 64B-contiguous);
//  - full N per block -> z written complete (k34 reads scalar). ----
#define BM3 64
__global__ __launch_bounds__(512) void k2_z_bf(
    const ushort_t* __restrict__ Ebf, const ushort_t* __restrict__ WvT,
    const float* __restrict__ hidden_ws, const float* __restrict__ bv,
    const float* __restrict__ Wav, float* __restrict__ z_ws)
{
    __shared__ ushort_t As[8][BM3 * 64];   // 8 x 8 KB = 64 KB
    __shared__ float hv_s[2][A_];          // 4 KB
    __shared__ float wav_s[A_];            // 2 KB
    __shared__ float zpart[4][BM3];        // 1 KB

    int tid = threadIdx.x;
    int m0 = blockIdx.x * BM3;
    int b0 = m0 / P_, b1 = (m0 + BM3 - 1) / P_;

    {
        int a = tid;
        float bva = bv[a];
        hv_s[0][a] = hidden_ws[(size_t)b0 * A_ + a] + bva;
        hv_s[1][a] = hidden_ws[(size_t)b1 * A_ + a] + bva;
        wav_s[a]   = Wav[a];
    }

    int lane = tid & 63, w = tid >> 6;
    int wm = w & 1, wn = w >> 1;
    int col = lane & 15, q = lane >> 4;

    // ---- stage all 8 K-chunks of the A strip (r2 staging map; 512
    // threads cover 64 rows x 8 slots in one instruction per chunk) ----
    {
        int sr = tid >> 3, spos = tid & 7;           // row 0..63, slot 0..7
        int gch = spos ^ (sr & 7);                   // inverse swizzle
        const ushort_t* agb = Ebf + (size_t)(m0 + sr) * D_ + gch * 8;
#pragma unroll
        for (int kt = 0; kt < 8; ++kt)
            async_load16(agb + kt * 64, &As[kt][0] + tid * 8);
    }
    asm volatile("s_waitcnt vmcnt(0)" ::: "memory");
    __builtin_amdgcn_s_barrier();

    f32x4 acc[2][8];
#pragma unroll
    for (int tm = 0; tm < 2; ++tm)
#pragma unroll
        for (int tn = 0; tn < 8; ++tn)
            acc[tm][tn] = (f32x4){0.f, 0.f, 0.f, 0.f};

    int fx = col & 7;
    const ushort_t* bgp = WvT + (size_t)(wn * 128 + col) * D_ + q * 8;

    // ---- barrier-free K-loop: A from LDS (r2 offsets), B from L2 ----
#pragma unroll
    for (int k32 = 0; k32 < 16; ++k32) {
        int kt = k32 >> 1, ks = k32 & 1;
        bf16x8 afr[2];
#pragma unroll
        for (int tm = 0; tm < 2; ++tm)
            afr[tm] = *(const bf16x8*)(&As[kt][0]
                + (wm * 32 + tm * 16 + col) * 64 + (((ks * 4 + q) ^ fx) * 8));
#pragma unroll
        for (int tn = 0; tn < 8; ++tn) {
            bf16x8 bfr = *(const bf16x8*)(bgp + (size_t)tn * 16 * D_ + k32 * 32);
#pragma unroll
            for (int tm = 0; tm < 2; ++tm)
                acc[tm][tn] = __builtin_amdgcn_mfma_f32_16x16x32_bf16(
                    afr[tm], bfr, acc[tm][tn], 0, 0, 0);
        }
    }

    // ---- epilogue: z rows complete in-block ----
#pragma unroll
    for (int tm = 0; tm < 2; ++tm) {
#pragma unroll
        for (int r = 0; r < 4; ++r) {
            int row = wm * 32 + tm * 16 + q * 4 + r;
            int bsel = ((m0 + row) / P_) - b0;
            float zr = 0.f;
#pragma unroll
            for (int tn = 0; tn < 8; ++tn) {
                int nl = wn * 128 + tn * 16 + col;
                zr += wav_s[nl] * tanh_fast(acc[tm][tn][r] + hv_s[bsel][nl]);
            }
#pragma unroll
            for (int msk = 1; msk < 16; msk <<= 1)
                zr += __shfl_xor(zr, msk, 64);
            if (col == 0) zpart[wn][row] = zr;
        }
    }
    __syncthreads();
    if (tid < BM3)
        z_ws[m0 + tid] = zpart[0][tid] + zpart[1][tid]
                       + zpart[2][tid] + zpart[3][tid];
}

// ---- K34: fused s_att + softmax + c_t GEMV + mixing.  One block per batch,
// 512 threads (8 waves).  z is a complete scalar per row. ----
__global__ __launch_bounds__(512) void k34_softmax_ct(
    const ushort_t* __restrict__ Ebf, const float* __restrict__ st,
    const float* __restrict__ z_ws, const float* __restrict__ hidden_ws,
    const float* __restrict__ s_ws, const float* __restrict__ Was,
    const float* __restrict__ bas, const float* __restrict__ bav,
    float* __restrict__ out)
{
    __shared__ float red[8];
    __shared__ float al[P_];
    __shared__ float acc_s[8][516];   // +4 pad
    __shared__ float bm_s, bl_s, sa_s;

    int b = blockIdx.x, t = threadIdx.x;
    int lane = t & 63, w = t >> 6;

    // ---- s_att = Was . tanh(s + hidden) + bas ----
    float part = Was[t] * tanh_fast(s_ws[(size_t)b * A_ + t]
                                  + hidden_ws[(size_t)b * A_ + t]);
#pragma unroll
    for (int o = 32; o >= 1; o >>= 1) part += __shfl_down(part, o, 64);
    if (lane == 0) red[w] = part;
    __syncthreads();
    if (t == 0) {
        float s = 0.f;
#pragma unroll
        for (int i = 0; i < 8; ++i) s += red[i];
        sa_s = s + bas[0];
    }
    __syncthreads();

    // ---- softmax over z (P=196) ----
    float zv = (t < P_) ? (z_ws[(size_t)b * P_ + t] + bav[0]) : -1e30f;
    float m = zv;
#pragma unroll
    for (int o = 32; o >= 1; o >>= 1) m = fmaxf(m, __shfl_xor(m, o, 64));
    if (lane == 0) red[w] = m;
    __syncthreads();
    if (t == 0) {
        float mm = red[0];
#pragma unroll
        for (int i = 1; i < 8; ++i) mm = fmaxf(mm, red[i]);
        bm_s = mm;
    }
    __syncthreads();
    float m1 = bm_s;
    float e = (t < P_) ? __expf(zv - m1) : 0.f;
    float s = e;
#pragma unroll
    for (int o = 32; o >= 1; o >>= 1) s += __shfl_xor(s, o, 64);
    if (lane == 0) red[w] = s;
    __syncthreads();
    if (t == 0) {
        float ss = 0.f;
#pragma unroll
        for (int i = 0; i < 8; ++i) ss += red[i];
        bl_s = ss;
    }
    __syncthreads();
    float l1 = bl_s;
    if (t < P_) {
        float alpha = e / l1;
        al[t] = alpha;
        out[OUT_ALPHA + (size_t)b * P_ + t] = alpha;
    }
    float sa = sa_s;
    float m2 = fmaxf(m1, sa);
    float eb2 = __expf(sa - m2);
    float l2 = __expf(m1 - m2) * l1 + eb2;
    float beta = eb2 / l2;
    if (t == 0) out[OUT_BETA + b] = beta;
    __syncthreads();   // al[] ready

    // ---- c_t = E[b]^T alpha ----
    float ac[8] = {0.f, 0.f, 0.f, 0.f, 0.f, 0.f, 0.f, 0.f};
    const uint4* eb = (const uint4*)(Ebf + (size_t)b * P_ * D_);
#pragma unroll 4
    for (int i = 0; i < 24; ++i) {
        int pp = w + 8 * i;
        uint4 v = eb[(size_t)pp * (D_ / 8) + lane];
        fma8(al[pp], v, ac);
    }
    if (w < P_ - 192) {        // tail rows 192..195
        int pp = 192 + w;
        uint4 v = eb[(size_t)pp * (D_ / 8) + lane];
        fma8(al[pp], v, ac);
    }
#pragma unroll
    for (int j = 0; j < 8; ++j) acc_s[w][lane * 8 + j] = ac[j];
    __syncthreads();
    float c = 0.f;
#pragma unroll
    for (int g = 0; g < 8; ++g) c += acc_s[g][t];
    float sv = st[(size_t)b * D_ + t];
    out[OUT_CHAT + (size_t)b * D_ + t] = beta * sv + (1.f - beta) * c;
}

extern "C" void kernel_launch(void* const* d_in, const int* in_sizes, int n_in,
                              void* d_out, int out_size, void* d_ws, size_t ws_size,
                              hipStream_t stream)
{
    (void)in_sizes; (void)n_in; (void)out_size; (void)ws_size;
    const float* E   = (const float*)d_in[0];
    const float* dh  = (const float*)d_in[1];
    const float* st  = (const float*)d_in[2];
    const float* Wv  = (const float*)d_in[3];
    const float* bv  = (const float*)d_in[4];
    const float* Wh  = (const float*)d_in[5];
    const float* bh  = (const float*)d_in[6];
    const float* Ws  = (const float*)d_in[7];
    const float* bs  = (const float*)d_in[8];
    const float* Wav = (const float*)d_in[9];
    const float* bav = (const float*)d_in[10];
    const float* Was = (const float*)d_in[11];
    const float* bas = (const float*)d_in[12];
    float* out = (float*)d_out;

    char* ws = (char*)d_ws;
    ushort_t* WvT     = (ushort_t*)(ws);            //  524288, live thru k2
    ushort_t* WhT     = (ushort_t*)(ws + 524288);   //  524288, dead after k1
    ushort_t* WsT     = (ushort_t*)(ws + 1048576);  //  524288, dead after k1
    // z (200704 B, [B*P] f32) aliases WhT — written by k2, after k1
    float*    z_w     = (float*)(ws + 524288);
    ushort_t* dhbf    = (ushort_t*)(ws + 1572864);  //  262144
    ushort_t* stbf    = (ushort_t*)(ws + 1835008);  //  262144
    float*    hidden_w= (float*)(ws + 2097152);     //  524288
    float*    s_w     = (float*)(ws + 2621440);     //  524288
    ushort_t* Ebf     = (ushort_t*)(ws + 3145728);  // 51380224 (total ~52 MB)

    k_prep<<<12544 + 128 + 768, 256, 0, stream>>>(E, dh, st, Wv, Wh, Ws,
                                                  Ebf, dhbf, stbf, WvT, WhT, WsT);
    k1_mfma<<<dim3(4, 2, 2), 256, 0, stream>>>(dhbf, stbf, WhT, WsT, bh, bs,
                                               hidden_w, s_w);
    k2_z_bf<<<(B_ * P_) / BM3, 512, 0, stream>>>(
        Ebf, WvT, hidden_w, bv, Wav, z_w);
    k34_softmax_ct<<<256, 512, 0, stream>>>(Ebf, st, z_w, hidden_w, s_w,
                                            Was, bas, bav, out);
}

// Round 10
// 246.742 us; speedup vs baseline: 1.3453x; 1.3453x over previous
//
#include <hip/hip_runtime.h>
#include <hip/hip_bf16.h>
#include <cstdint>

#define B_ 256
#define P_ 196
#define D_ 512
#define A_ 512

#define OUT_CHAT  0
#define OUT_ALPHA (B_*D_)            // 131072
#define OUT_BETA  (B_*D_ + B_*P_)    // 181248

typedef unsigned short ushort_t;
typedef uint32_t u32;
typedef uint64_t u64;
typedef __attribute__((ext_vector_type(8))) __bf16 bf16x8;
typedef __attribute__((ext_vector_type(4))) float f32x4;

__device__ __forceinline__ ushort_t f2bf(float f) {
    union { float f; u32 i; } v; v.f = f;
    u32 r = (v.i + 0x7fffu + ((v.i >> 16) & 1u)) >> 16;
    return (ushort_t)r;
}
__device__ __forceinline__ float bfbits2f(u32 lo16) {
    union { u32 i; float f; } v; v.i = lo16 << 16; return v.f;
}
// HW packed f32->bf16 (v_cvt_pk_bf16_f32 on gfx950)
__device__ __forceinline__ u32 cvt2bf(float x, float y) {
    union { __hip_bfloat162 h; u32 u; } v;
    v.h = __float22bfloat162_rn(make_float2(x, y));
    return v.u;
}
__device__ __forceinline__ float tanh_fast(float x) {
    float e = __expf(2.0f * x);
    return 1.0f - 2.0f / (e + 1.0f);
}
// async 16B global->LDS (global_load_lds_dwordx4); LDS dest is effectively
// wave-uniform base (first lane) + lane*16 — our per-lane lds ptrs match
// that mapping (same idiom as the r0-r2 kernels that passed correctness).
__device__ __forceinline__ void async_load16(const ushort_t* g, ushort_t* l) {
    __builtin_amdgcn_global_load_lds(
        (const __attribute__((address_space(1))) unsigned int*)g,
        (__attribute__((address_space(3))) unsigned int*)l, 16, 0, 0);
}
__device__ __forceinline__ void fma8(float ap, uint4 v, float ac[8]) {
    ac[0] = fmaf(ap, bfbits2f(v.x & 0xffffu), ac[0]);
    ac[1] = fmaf(ap, bfbits2f(v.x >> 16),     ac[1]);
    ac[2] = fmaf(ap, bfbits2f(v.y & 0xffffu), ac[2]);
    ac[3] = fmaf(ap, bfbits2f(v.y >> 16),     ac[3]);
    ac[4] = fmaf(ap, bfbits2f(v.z & 0xffffu), ac[4]);
    ac[5] = fmaf(ap, bfbits2f(v.z >> 16),     ac[5]);
    ac[6] = fmaf(ap, bfbits2f(v.w & 0xffffu), ac[6]);
    ac[7] = fmaf(ap, bfbits2f(v.w >> 16),     ac[7]);
}

// ---- k_prep: [0,12544) Ebf=bf16(E); [12544,12672) dh/st cvt;
//              [12672,13440) transposes WT[a][d]=bf16(W[d][a]) ----
__global__ __launch_bounds__(256) void k_prep(
    const float* __restrict__ E, const float* __restrict__ dh,
    const float* __restrict__ st,
    const float* __restrict__ Wv, const float* __restrict__ Wh,
    const float* __restrict__ Ws,
    ushort_t* __restrict__ Ebf, ushort_t* __restrict__ dhbf,
    ushort_t* __restrict__ stbf,
    ushort_t* __restrict__ WvT, ushort_t* __restrict__ WhT,
    ushort_t* __restrict__ WsT)
{
    __shared__ ushort_t tile[32][33];
    int bx = blockIdx.x;
    if (bx < 12544) {
        size_t i0 = (size_t)bx * 512 + threadIdx.x;
        const float4* src = (const float4*)E;
        u64* dst = (u64*)Ebf;
        float4 v0 = src[i0];
        float4 v1 = src[i0 + 256];
        dst[i0]       = (u64)cvt2bf(v0.x, v0.y) | ((u64)cvt2bf(v0.z, v0.w) << 32);
        dst[i0 + 256] = (u64)cvt2bf(v1.x, v1.y) | ((u64)cvt2bf(v1.z, v1.w) << 32);
    } else if (bx < 12672) {
        int gid = (bx - 12544) * 256 + threadIdx.x;   // 0..32767
        float4 dv = ((const float4*)dh)[gid];
        float4 sv = ((const float4*)st)[gid];
        ((u64*)dhbf)[gid] = (u64)cvt2bf(dv.x, dv.y) | ((u64)cvt2bf(dv.z, dv.w) << 32);
        ((u64*)stbf)[gid] = (u64)cvt2bf(sv.x, sv.y) | ((u64)cvt2bf(sv.z, sv.w) << 32);
    } else {
        int idx = bx - 12672;            // 0..767
        int z   = idx >> 8;              // which matrix
        int rem = idx & 255;
        int tby = rem >> 4, tbx = rem & 15;
        const float* W  = (z == 0) ? Wv  : (z == 1) ? Wh  : Ws;
        ushort_t*    WT = (z == 0) ? WvT : (z == 1) ? WhT : WsT;
        int t = threadIdx.x, r = t >> 5, c = t & 31;
#pragma unroll
        for (int i = 0; i < 4; ++i) {
            int row = r + 8 * i;
            tile[row][c] = f2bf(W[(size_t)(tby * 32 + row) * A_ + tbx * 32 + c]);
        }
        __syncthreads();
#pragma unroll
        for (int i = 0; i < 4; ++i) {
            int row = r + 8 * i;
            WT[(size_t)(tbx * 32 + row) * D_ + tby * 32 + c] = tile[c][row];
        }
    }
}

#define PADK 72   // used by k1 only

// ---- k1_mfma: hidden = dh@Wh+bh (z=0) and s = st@Ws+bs (z=1) ----
__global__ __launch_bounds__(256) void k1_mfma(
    const ushort_t* __restrict__ dhbf, const ushort_t* __restrict__ stbf,
    const ushort_t* __restrict__ WhT,  const ushort_t* __restrict__ WsT,
    const float* __restrict__ bh, const float* __restrict__ bs,
    float* __restrict__ hidden_ws, float* __restrict__ s_ws)
{
    __shared__ ushort_t As[128 * PADK];
    __shared__ ushort_t Bs[128 * PADK];

    int mat = blockIdx.z;
    const ushort_t* Abf = mat ? stbf : dhbf;
    const ushort_t* WT  = mat ? WsT  : WhT;
    const float*    bia = mat ? bs   : bh;
    float*          outp = mat ? s_ws : hidden_ws;

    int tid = threadIdx.x;
    int m0 = blockIdx.y * 128;
    int n0 = blockIdx.x * 128;

    int lane = tid & 63, w = tid >> 6;
    int wm = w & 1, wn = w >> 1;
    int col = lane & 15, q = lane >> 4;

    f32x4 acc[4][4];
#pragma unroll
    for (int tm = 0; tm < 4; ++tm)
#pragma unroll
        for (int tn = 0; tn < 4; ++tn)
            acc[tm][tn] = (f32x4){0.f, 0.f, 0.f, 0.f};

    const ushort_t* arow = As + (wm * 64 + col) * PADK + q * 8;
    const ushort_t* brow = Bs + (wn * 64 + col) * PADK + q * 8;

    int sr = tid >> 3, sc = tid & 7;
    for (int kt = 0; kt < D_ / 64; ++kt) {
#pragma unroll
        for (int i = 0; i < 4; ++i) {
            int row = sr + i * 32;
            *(uint4*)(As + row * PADK + sc * 8) =
                *(const uint4*)(Abf + (size_t)(m0 + row) * D_ + kt * 64 + sc * 8);
            *(uint4*)(Bs + row * PADK + sc * 8) =
                *(const uint4*)(WT + (size_t)(n0 + row) * D_ + kt * 64 + sc * 8);
        }
        __syncthreads();
#pragma unroll
        for (int ks = 0; ks < 2; ++ks) {
            bf16x8 afr[4];
#pragma unroll
            for (int tm = 0; tm < 4; ++tm)
                afr[tm] = *(const bf16x8*)(arow + tm * 16 * PADK + ks * 32);
#pragma unroll
            for (int tn = 0; tn < 4; ++tn) {
                bf16x8 bfr = *(const bf16x8*)(brow + tn * 16 * PADK + ks * 32);
#pragma unroll
                for (int tm = 0; tm < 4; ++tm)
                    acc[tm][tn] = __builtin_amdgcn_mfma_f32_16x16x32_bf16(
                        afr[tm], bfr, acc[tm][tn], 0, 0, 0);
            }
        }
        __syncthreads();
    }

#pragma unroll
    for (int tm = 0; tm < 4; ++tm)
#pragma unroll
        for (int r = 0; r < 4; ++r) {
            int b = m0 + wm * 64 + tm * 16 + q * 4 + r;
#pragma unroll
            for (int tn = 0; tn < 4; ++tn) {
                int n = n0 + wn * 64 + tn * 16 + col;
                outp[(size_t)b * A_ + n] = acc[tm][tn][r] + bia[n];
            }
        }
}

// ---- K2: round-0's kernel VERBATIM (best-measured k2: never exceeded
// the 59.8us fills in r0; staged traffic 309MB vs r2/r7's 401MB).
// BM=128, BN=256, BK=64, natural dim3(392,2) grid, single-buffer
// async-LDS staging.  Three restructures (r4 small-phase, r8 flat
// layout, r9 B-direct) all regressed — this structure stands. ----
#define BM 128
#define BN 256
#define BKk 64
__global__ __launch_bounds__(256, 3) void k2_z_bf(
    const ushort_t* __restrict__ Ebf, const ushort_t* __restrict__ WvT,
    const float* __restrict__ hidden_ws, const float* __restrict__ bv,
    const float* __restrict__ Wav, float* __restrict__ z2_ws)
{
    __shared__ ushort_t As[BM * BKk];   // 16 KB
    __shared__ ushort_t Bs[BN * BKk];   // 32 KB
    __shared__ float hv_s[2][BN];
    __shared__ float wav_s[BN];
    __shared__ float zpart[2][BM];

    int tid = threadIdx.x;
    int m0  = blockIdx.x * BM;
    int n0  = blockIdx.y * BN;
    int b0  = m0 / P_;
    int b1  = (m0 + BM - 1) / P_;

    {
        int a = n0 + tid;
        float bva = bv[a];
        hv_s[0][tid] = hidden_ws[(size_t)b0 * A_ + a] + bva;
        hv_s[1][tid] = hidden_ws[(size_t)b1 * A_ + a] + bva;
        wav_s[tid]   = Wav[a];
    }

    int lane = tid & 63, w = tid >> 6;
    int wm = w & 1, wn = w >> 1;
    int col = lane & 15, q = lane >> 4;

    f32x4 acc[4][8];
#pragma unroll
    for (int tm = 0; tm < 4; ++tm)
#pragma unroll
        for (int tn = 0; tn < 8; ++tn)
            acc[tm][tn] = (f32x4){0.f, 0.f, 0.f, 0.f};

    int srow = tid >> 3, spos = tid & 7;
    int gch  = spos ^ (srow & 7);
    const ushort_t* agb = Ebf + (size_t)(m0 + srow) * D_ + gch * 8;
    const ushort_t* bgb = WvT + (size_t)(n0 + srow) * D_ + gch * 8;
    ushort_t* alb = As + tid * 8;
    ushort_t* blb = Bs + tid * 8;

    int fx = col & 7;

    for (int kt = 0; kt < D_ / BKk; ++kt) {
#pragma unroll
        for (int i = 0; i < 4; ++i)
            async_load16(agb + (size_t)i * 32 * D_ + kt * BKk, alb + i * 2048);
#pragma unroll
        for (int i = 0; i < 8; ++i)
            async_load16(bgb + (size_t)i * 32 * D_ + kt * BKk, blb + i * 2048);
        __syncthreads();
#pragma unroll
        for (int ks = 0; ks < 2; ++ks) {
            bf16x8 afr[4];
#pragma unroll
            for (int tm = 0; tm < 4; ++tm)
                afr[tm] = *(const bf16x8*)(As + (wm * 64 + tm * 16 + col) * BKk
                                              + (((ks * 4 + q) ^ fx) * 8));
#pragma unroll
            for (int tn = 0; tn < 8; ++tn) {
                bf16x8 bfr = *(const bf16x8*)(Bs + (wn * 128 + tn * 16 + col) * BKk
                                                 + (((ks * 4 + q) ^ fx) * 8));
#pragma unroll
                for (int tm = 0; tm < 4; ++tm)
                    acc[tm][tn] = __builtin_amdgcn_mfma_f32_16x16x32_bf16(
                        afr[tm], bfr, acc[tm][tn], 0, 0, 0);
            }
        }
        __syncthreads();
    }

#pragma unroll
    for (int tm = 0; tm < 4; ++tm) {
#pragma unroll
        for (int r = 0; r < 4; ++r) {
            int row = wm * 64 + tm * 16 + q * 4 + r;
            int m   = m0 + row;
            int bsel = (m / P_) - b0;
            float zr = 0.f;
#pragma unroll
            for (int tn = 0; tn < 8; ++tn) {
                int nl = wn * 128 + tn * 16 + col;
                zr += wav_s[nl] * tanh_fast(acc[tm][tn][r] + hv_s[bsel][nl]);
            }
#pragma unroll
            for (int msk = 1; msk < 16; msk <<= 1)
                zr += __shfl_xor(zr, msk, 64);
            if (col == 0) zpart[wn][row] = zr;
        }
    }
    __syncthreads();
    if (tid < BM)
        z2_ws[(size_t)blockIdx.y * (B_ * P_) + m0 + tid] =
            zpart[0][tid] + zpart[1][tid];
}

// ---- K34: round-1's fused kernel VERBATIM (s_att + softmax + c_t GEMV
// + mixing; one 512-thread block per batch; 2-slice z2 read). ----
__global__ __launch_bounds__(512) void k34_softmax_ct(
    const ushort_t* __restrict__ Ebf, const float* __restrict__ st,
    const float* __restrict__ z2_ws, const float* __restrict__ hidden_ws,
    const float* __restrict__ s_ws, const float* __restrict__ Was,
    const float* __restrict__ bas, const float* __restrict__ bav,
    float* __restrict__ out)
{
    __shared__ float red[8];
    __shared__ float al[P_];
    __shared__ float acc_s[8][516];   // +4 pad
    __shared__ float bm_s, bl_s, sa_s;

    int b = blockIdx.x, t = threadIdx.x;
    int lane = t & 63, w = t >> 6;

    // ---- s_att = Was . tanh(s + hidden) + bas ----
    float part = Was[t] * tanh_fast(s_ws[(size_t)b * A_ + t]
                                  + hidden_ws[(size_t)b * A_ + t]);
#pragma unroll
    for (int o = 32; o >= 1; o >>= 1) part += __shfl_down(part, o, 64);
    if (lane == 0) red[w] = part;
    __syncthreads();
    if (t == 0) {
        float s = 0.f;
#pragma unroll
        for (int i = 0; i < 8; ++i) s += red[i];
        sa_s = s + bas[0];
    }
    __syncthreads();

    // ---- softmax over z (P=196); z = sum of 2 n-slice partials ----
    float zv = (t < P_) ? (z2_ws[(size_t)b * P_ + t]
                         + z2_ws[(size_t)(B_ * P_) + (size_t)b * P_ + t] + bav[0])
                        : -1e30f;
    float m = zv;
#pragma unroll
    for (int o = 32; o >= 1; o >>= 1) m = fmaxf(m, __shfl_xor(m, o, 64));
    if (lane == 0) red[w] = m;
    __syncthreads();
    if (t == 0) {
        float mm = red[0];
#pragma unroll
        for (int i = 1; i < 8; ++i) mm = fmaxf(mm, red[i]);
        bm_s = mm;
    }
    __syncthreads();
    float m1 = bm_s;
    float e = (t < P_) ? __expf(zv - m1) : 0.f;
    float s = e;
#pragma unroll
    for (int o = 32; o >= 1; o >>= 1) s += __shfl_xor(s, o, 64);
    if (lane == 0) red[w] = s;
    __syncthreads();
    if (t == 0) {
        float ss = 0.f;
#pragma unroll
        for (int i = 0; i < 8; ++i) ss += red[i];
        bl_s = ss;
    }
    __syncthreads();
    float l1 = bl_s;
    if (t < P_) {
        float alpha = e / l1;
        al[t] = alpha;
        out[OUT_ALPHA + (size_t)b * P_ + t] = alpha;
    }
    float sa = sa_s;
    float m2 = fmaxf(m1, sa);
    float eb2 = __expf(sa - m2);
    float l2 = __expf(m1 - m2) * l1 + eb2;
    float beta = eb2 / l2;
    if (t == 0) out[OUT_BETA + b] = beta;
    __syncthreads();   // al[] ready

    // ---- c_t = E[b]^T alpha ----
    float ac[8] = {0.f, 0.f, 0.f, 0.f, 0.f, 0.f, 0.f, 0.f};
    const uint4* eb = (const uint4*)(Ebf + (size_t)b * P_ * D_);
#pragma unroll 4
    for (int i = 0; i < 24; ++i) {
        int pp = w + 8 * i;
        uint4 v = eb[(size_t)pp * (D_ / 8) + lane];
        fma8(al[pp], v, ac);
    }
    if (w < P_ - 192) {        // tail rows 192..195
        int pp = 192 + w;
        uint4 v = eb[(size_t)pp * (D_ / 8) + lane];
        fma8(al[pp], v, ac);
    }
#pragma unroll
    for (int j = 0; j < 8; ++j) acc_s[w][lane * 8 + j] = ac[j];
    __syncthreads();
    float c = 0.f;
#pragma unroll
    for (int g = 0; g < 8; ++g) c += acc_s[g][t];
    float sv = st[(size_t)b * D_ + t];
    out[OUT_CHAT + (size_t)b * D_ + t] = beta * sv + (1.f - beta) * c;
}

extern "C" void kernel_launch(void* const* d_in, const int* in_sizes, int n_in,
                              void* d_out, int out_size, void* d_ws, size_t ws_size,
                              hipStream_t stream)
{
    (void)in_sizes; (void)n_in; (void)out_size; (void)ws_size;
    const float* E   = (const float*)d_in[0];
    const float* dh  = (const float*)d_in[1];
    const float* st  = (const float*)d_in[2];
    const float* Wv  = (const float*)d_in[3];
    const float* bv  = (const float*)d_in[4];
    const float* Wh  = (const float*)d_in[5];
    const float* bh  = (const float*)d_in[6];
    const float* Ws  = (const float*)d_in[7];
    const float* bs  = (const float*)d_in[8];
    const float* Wav = (const float*)d_in[9];
    const float* bav = (const float*)d_in[10];
    const float* Was = (const float*)d_in[11];
    const float* bas = (const float*)d_in[12];
    float* out = (float*)d_out;

    char* ws = (char*)d_ws;
    ushort_t* WvT     = (ushort_t*)(ws);            //  524288, live thru k2
    ushort_t* WhT     = (ushort_t*)(ws + 524288);   //  524288, dead after k1
    ushort_t* WsT     = (ushort_t*)(ws + 1048576);  //  524288, dead after k1
    // z2 (802816 B, 2 x [B*P] f32) aliases WhT+WsT — written by k2, after k1
    float*    z2_w    = (float*)(ws + 524288);
    ushort_t* dhbf    = (ushort_t*)(ws + 1572864);  //  262144
    ushort_t* stbf    = (ushort_t*)(ws + 1835008);  //  262144
    float*    hidden_w= (float*)(ws + 2097152);     //  524288
    float*    s_w     = (float*)(ws + 2621440);     //  524288
    ushort_t* Ebf     = (ushort_t*)(ws + 3145728);  // 51380224 (total ~52 MB)

    k_prep<<<12544 + 128 + 768, 256, 0, stream>>>(E, dh, st, Wv, Wh, Ws,
                                                  Ebf, dhbf, stbf, WvT, WhT, WsT);
    k1_mfma<<<dim3(4, 2, 2), 256, 0, stream>>>(dhbf, stbf, WhT, WsT, bh, bs,
                                               hidden_w, s_w);
    k2_z_bf<<<dim3((B_ * P_) / BM, A_ / BN), 256, 0, stream>>>(
        Ebf, WvT, hidden_w, bv, Wav, z2_w);
    k34_softmax_ct<<<256, 512, 0, stream>>>(Ebf, st, z2_w, hidden_w, s_w,
                                            Was, bas, bav, out);
}